// Round 16
// baseline (25.690 us; speedup 1.0000x reference)
//
#include <hip/hip_runtime.h>
#include <math.h>

// v_sad_u8: d = c + sum_k |a.byte[k] - b.byte[k]|
__device__ __forceinline__ unsigned sad8(unsigned a, unsigned b, unsigned c) {
    unsigned d;
    asm("v_sad_u8 %0, %1, %2, %3" : "=v"(d) : "v"(a), "v"(b), "v"(c));
    return d;
}

// quad-perm DPP butterfly add over lane quads (pure VALU)
__device__ __forceinline__ unsigned quad_reduce_add(unsigned v) {
    unsigned t = (unsigned)__builtin_amdgcn_mov_dpp((int)v, 0xB1, 0xF, 0xF, false); // [1,0,3,2]
    v += t;
    t = (unsigned)__builtin_amdgcn_mov_dpp((int)v, 0x4E, 0xF, 0xF, false);          // [2,3,0,1]
    return v + t;
}

// ---- prepass: sigmoid -> u8; A row-major, B transposed [chunk][col]; row sums ----
__global__ __launch_bounds__(256)
void prepass(const float* __restrict__ x1, const float* __restrict__ x2,
             unsigned* __restrict__ Aq, unsigned* __restrict__ Bt,
             float* __restrict__ rs) {
    const int wid = threadIdx.x >> 6, lane = threadIdx.x & 63;
    const int r = blockIdx.x * 4 + wid;            // 0..2047
    const bool isA = (r < 1024);
    const int row = isA ? r : (r - 1024);
    const float* src = (isA ? x1 : x2) + (size_t)row * 256;

    float4 g = *(const float4*)(src + 4 * lane);
    const float k = 255.0f;
    unsigned q0 = (unsigned)(k / (1.0f + __expf(-g.x)) + 0.5f);
    unsigned q1 = (unsigned)(k / (1.0f + __expf(-g.y)) + 0.5f);
    unsigned q2 = (unsigned)(k / (1.0f + __expf(-g.z)) + 0.5f);
    unsigned q3 = (unsigned)(k / (1.0f + __expf(-g.w)) + 0.5f);
    const unsigned packed = q0 | (q1 << 8) | (q2 << 16) | (q3 << 24);

    if (isA) {
        Aq[(size_t)row * 64 + lane] = packed;                         // row-major
    } else {
        // Bt: uint4 chunk c of column `row` lives at BtU4[c*1024 + row]
        Bt[(size_t)(lane >> 2) * 4096 + (size_t)row * 4 + (lane & 3)] = packed;
    }

    int sum = (int)(q0 + q1 + q2 + q3);
    #pragma unroll
    for (int s = 32; s >= 1; s >>= 1)
        sum += __shfl_xor(sum, s, 64);
    if (lane == 0) rs[r] = (float)sum;             // <= 65280: f32-exact
}

// ---- main: zero LDS, zero barriers. lane = (ql, tx, ty); quarter in lane quads.
// Operands straight from L2; cross-quarter reduce via DPP. ----
__global__ __launch_bounds__(256, 4)
void jaccard_main(const uint4* __restrict__ AqU4, const uint4* __restrict__ BtU4,
                  const float* __restrict__ rs, float* __restrict__ out) {
    const int bi = blockIdx.x;        // 0..63 : 16-row stripes
    const int bj = blockIdx.y;        // 0..15 : 64-col stripes
    const int tid  = threadIdx.x;
    const int lane = tid & 63;
    const int w    = tid >> 6;        // 0..3

    const int ql = lane & 3;          // D-quarter: chunks [4ql, 4ql+4)
    const int tx = (lane >> 2) & 3;   // cols {tx + 4n}
    const int ty = lane >> 4;         // rows {ty + 4m}

    const int arow0 = bi * 16 + ty;             // + 4m
    const int col0  = bj * 64 + 16 * w + tx;    // + 4n

    unsigned acc[4][4] = {};
    #pragma unroll
    for (int cc = 0; cc < 4; ++cc) {
        const int c = ql * 4 + cc;              // 16B chunk index 0..15
        uint4 av[4], bv[4];
        #pragma unroll
        for (int m = 0; m < 4; ++m)
            av[m] = AqU4[(size_t)(arow0 + 4 * m) * 16 + c];      // 16 addrs/wave
        #pragma unroll
        for (int n = 0; n < 4; ++n)
            bv[n] = BtU4[(size_t)c * 1024 + col0 + 4 * n];       // 16 addrs/wave
        #pragma unroll
        for (int m = 0; m < 4; ++m)
            #pragma unroll
            for (int n = 0; n < 4; ++n) {
                unsigned a = acc[m][n];
                a = sad8(av[m].x, bv[n].x, a);
                a = sad8(av[m].y, bv[n].y, a);
                a = sad8(av[m].z, bv[n].z, a);
                a = sad8(av[m].w, bv[n].w, a);
                acc[m][n] = a;
            }
    }

    // ---- cross-quarter reduce (DPP over lane quads); lane ql keeps m = ql ----
    unsigned sd[4];
    #pragma unroll
    for (int n = 0; n < 4; ++n) {
        unsigned r0 = quad_reduce_add(acc[0][n]);
        unsigned r1 = quad_reduce_add(acc[1][n]);
        unsigned r2 = quad_reduce_add(acc[2][n]);
        unsigned r3 = quad_reduce_add(acc[3][n]);
        sd[n] = ql < 2 ? (ql == 0 ? r0 : r1) : (ql == 2 ? r2 : r3);  // static + cndmask
    }

    // ---- epilogue: this lane owns row i = arow0 + 4*ql, cols col0 + 4n ----
    const int i = arow0 + 4 * ql;
    const float sa = rs[i];
    float* outT = out + (size_t)1024 * 1024;

    #pragma unroll
    for (int n = 0; n < 4; ++n) {
        const int j = col0 + 4 * n;
        const float sb = rs[1024 + j];
        const float t  = sa + sb;
        const float in = 0.5f * (t - (float)sd[n]);
        const float v  = in / (t - in);
        out [(size_t)i * 1024 + j] = v;
        outT[(size_t)j * 1024 + i] = v;
    }
}

extern "C" void kernel_launch(void* const* d_in, const int* in_sizes, int n_in,
                              void* d_out, int out_size, void* d_ws, size_t ws_size,
                              hipStream_t stream) {
    const float* x1 = (const float*)d_in[0];
    const float* x2 = (const float*)d_in[1];
    float* out = (float*)d_out;

    unsigned* Aq = (unsigned*)d_ws;                 // 256 KB row-major u8 A
    unsigned* Bt = Aq + (size_t)1024 * 64;          // 256 KB transposed u8 B
    float*    rs = (float*)(Bt + (size_t)1024 * 64);// 8 KB row sums

    prepass<<<512, 256, 0, stream>>>(x1, x2, Aq, Bt, rs);
    jaccard_main<<<dim3(64, 16), 256, 0, stream>>>((const uint4*)Aq, (const uint4*)Bt,
                                                   rs, out);
}

// Round 17
// 18.978 us; speedup vs baseline: 1.3537x; 1.3537x over previous
//
#include <hip/hip_runtime.h>
#include <math.h>

#define RSTR  272                  // u8 tile row stride: 17 x 16B groups -> conflict-free b128
#define TILEB (32 * RSTR)          // 8704 B per tile (32 rows)
#define PSTR  136                  // partial stride: 4q*32B + 8 pad (2-way banks, free)

// v_sad_u8: d = c + sum_k |a.byte[k] - b.byte[k]|
__device__ __forceinline__ unsigned sad8(unsigned a, unsigned b, unsigned c) {
    unsigned d;
    asm("v_sad_u8 %0, %1, %2, %3" : "=v"(d) : "v"(a), "v"(b), "v"(c));
    return d;
}

// sum of 16 bytes of a uint4 (4 chained SADs vs 0)
__device__ __forceinline__ unsigned bytesum(uint4 v) {
    return sad8(v.x, 0u, sad8(v.y, 0u, sad8(v.z, 0u, sad8(v.w, 0u, 0u))));
}

// quantize 16 consecutive f32 (64B-aligned) -> 16 u8 (sigmoid * 255, rounded)
__device__ __forceinline__ uint4 quant16(const float* __restrict__ src) {
    uint4 r;
    unsigned q[4];
    #pragma unroll
    for (int c = 0; c < 4; ++c) {
        float4 g = *(const float4*)(src + 4 * c);
        const float k = 255.0f;
        unsigned q0 = (unsigned)(k / (1.0f + __expf(-g.x)) + 0.5f);
        unsigned q1 = (unsigned)(k / (1.0f + __expf(-g.y)) + 0.5f);
        unsigned q2 = (unsigned)(k / (1.0f + __expf(-g.z)) + 0.5f);
        unsigned q3 = (unsigned)(k / (1.0f + __expf(-g.w)) + 0.5f);
        q[c] = q0 | (q1 << 8) | (q2 << 16) | (q3 << 24);
    }
    r.x = q[0]; r.y = q[1]; r.z = q[2]; r.w = q[3];
    return r;
}

// ---- fused: quantize-staging + SAD inner + partial exchange, 4 blocks/CU ----
__global__ __launch_bounds__(256, 4)
void jaccard_kernel(const float* __restrict__ x1, const float* __restrict__ x2,
                    float* __restrict__ out) {
    __shared__ char ATile[TILEB];
    __shared__ char BTile[TILEB];
    __shared__ char Part[64 * PSTR];
    __shared__ unsigned ARS[32];     // A-row byte sums (u32, exact)
    __shared__ unsigned BRS[32];

    const int bi = blockIdx.x, bj = blockIdx.y;    // 32 x 32 tiles
    const int tid = threadIdx.x;

    if (tid < 32) { ARS[tid] = 0; BRS[tid] = 0; }
    __syncthreads();

    // ---- staging: sigmoid -> u8 -> LDS; row sums via SAD-vs-0 + LDS atomic ----
    #pragma unroll
    for (int k = 0; k < 2; ++k) {
        const int flat = tid + 256 * k;            // 0..511
        const int row = flat >> 4, c16 = flat & 15;
        const float* pa = x1 + (size_t)(bi * 32 + row) * 256 + c16 * 16;
        uint4 qa = quant16(pa);
        *(uint4*)(ATile + row * RSTR + c16 * 16) = qa;
        atomicAdd(&ARS[row], bytesum(qa));
        const float* pb = x2 + (size_t)(bj * 32 + row) * 256 + c16 * 16;
        uint4 qb = quant16(pb);
        *(uint4*)(BTile + row * RSTR + c16 * 16) = qb;
        atomicAdd(&BRS[row], bytesum(qb));
    }
    __syncthreads();

    // wave = one D-quarter q (bytes [64q,64q+64)); spatial 8x8, microtile 4x4
    const int s  = tid & 63;
    const int q  = tid >> 6;        // 0..3, wave-uniform
    const int tx = s & 7;           // cols {tx + 8n}
    const int ty = s >> 3;          // rows {ty + 8m}

    const char* ab = ATile + ty * RSTR + q * 64;
    const char* bb = BTile + tx * RSTR + q * 64;

    unsigned acc[4][4] = {};
    #pragma unroll
    for (int cc = 0; cc < 4; ++cc) {               // 4 x 16B chunks per quarter
        uint4 av[4], bv[4];
        #pragma unroll
        for (int m = 0; m < 4; ++m)
            av[m] = *(const uint4*)(ab + m * (8 * RSTR) + cc * 16);   // 8-addr broadcast
        #pragma unroll
        for (int n = 0; n < 4; ++n)
            bv[n] = *(const uint4*)(bb + n * (8 * RSTR) + cc * 16);   // 8-addr broadcast
        #pragma unroll
        for (int m = 0; m < 4; ++m)
            #pragma unroll
            for (int n = 0; n < 4; ++n) {
                unsigned a = acc[m][n];
                a = sad8(av[m].x, bv[n].x, a);
                a = sad8(av[m].y, bv[n].y, a);
                a = sad8(av[m].z, bv[n].z, a);
                a = sad8(av[m].w, bv[n].w, a);
                acc[m][n] = a;
            }
    }

    // ---- partials: u16-packed [s][q][m], b64 each; 136B stride -> 2-way banks ----
    {
        char* pw = Part + s * PSTR + q * 32;
        #pragma unroll
        for (int m = 0; m < 4; ++m) {
            unsigned p0 = acc[m][0] | (acc[m][1] << 16);   // each <= 16320
            unsigned p1 = acc[m][2] | (acc[m][3] << 16);
            *(uint2*)(pw + m * 8) = make_uint2(p0, p1);
        }
    }
    __syncthreads();

    // ---- reduce + epilogue: thread (s2, m2) owns row ty2+8*m2, cols {tx2+8n} ----
    const int s2 = tid & 63;
    const int m2 = tid >> 6;
    const int tx2 = s2 & 7;
    const int ty2 = s2 >> 3;

    unsigned sd0 = 0, sd1 = 0, sd2 = 0, sd3 = 0;
    const char* pr = Part + s2 * PSTR + m2 * 8;
    #pragma unroll
    for (int qq = 0; qq < 4; ++qq) {
        uint2 p = *(const uint2*)(pr + qq * 32);
        sd0 += p.x & 0xffff; sd1 += p.x >> 16;
        sd2 += p.y & 0xffff; sd3 += p.y >> 16;
    }

    const int i  = bi * 32 + ty2 + 8 * m2;
    const int j0 = bj * 32 + tx2;

    const float sa  = (float)ARS[ty2 + 8 * m2];
    const float sb0 = (float)BRS[tx2];
    const float sb1 = (float)BRS[tx2 + 8];
    const float sb2 = (float)BRS[tx2 + 16];
    const float sb3 = (float)BRS[tx2 + 24];

    const float t0 = sa + sb0, t1 = sa + sb1, t2 = sa + sb2, t3 = sa + sb3;
    const float i0 = 0.5f * (t0 - (float)sd0);
    const float i1 = 0.5f * (t1 - (float)sd1);
    const float i2 = 0.5f * (t2 - (float)sd2);
    const float i3 = 0.5f * (t3 - (float)sd3);
    const float v0 = i0 / (t0 - i0);
    const float v1 = i1 / (t1 - i1);
    const float v2 = i2 / (t2 - i2);
    const float v3 = i3 / (t3 - i3);

    float* outT = out + (size_t)1024 * 1024;
    out[(size_t)i * 1024 + j0]      = v0;
    out[(size_t)i * 1024 + j0 + 8]  = v1;
    out[(size_t)i * 1024 + j0 + 16] = v2;
    out[(size_t)i * 1024 + j0 + 24] = v3;
    outT[(size_t)j0        * 1024 + i] = v0;
    outT[(size_t)(j0 + 8)  * 1024 + i] = v1;
    outT[(size_t)(j0 + 16) * 1024 + i] = v2;
    outT[(size_t)(j0 + 24) * 1024 + i] = v3;
}

extern "C" void kernel_launch(void* const* d_in, const int* in_sizes, int n_in,
                              void* d_out, int out_size, void* d_ws, size_t ws_size,
                              hipStream_t stream) {
    const float* x1 = (const float*)d_in[0];
    const float* x2 = (const float*)d_in[1];
    float* out = (float*)d_out;

    jaccard_kernel<<<dim3(32, 32), 256, 0, stream>>>(x1, x2, out);
}

// Round 18
// 18.843 us; speedup vs baseline: 1.3634x; 1.0072x over previous
//
#include <hip/hip_runtime.h>
#include <math.h>

#define RSTR  272                  // B tile row stride: 17 x 16B groups -> even bank spread
#define TILEB (32 * RSTR)          // 8704 B (B tile only; no A tile, no Part)

// v_sad_u8: d = c + sum_k |a.byte[k] - b.byte[k]|
__device__ __forceinline__ unsigned sad8(unsigned a, unsigned b, unsigned c) {
    unsigned d;
    asm("v_sad_u8 %0, %1, %2, %3" : "=v"(d) : "v"(a), "v"(b), "v"(c));
    return d;
}

// quad-perm DPP butterfly add over lane quads (pure VALU, verified in R14)
__device__ __forceinline__ unsigned quad_reduce_add(unsigned v) {
    unsigned t = (unsigned)__builtin_amdgcn_mov_dpp((int)v, 0xB1, 0xF, 0xF, false); // [1,0,3,2]
    v += t;
    t = (unsigned)__builtin_amdgcn_mov_dpp((int)v, 0x4E, 0xF, 0xF, false);          // [2,3,0,1]
    return v + t;
}

// ---- prepass: sigmoid -> u8 (x255, round) + integer row sums (f32-exact) ----
__global__ __launch_bounds__(256)
void prepass(const float* __restrict__ x1, const float* __restrict__ x2,
             unsigned* __restrict__ Aq, unsigned* __restrict__ Bq,
             float* __restrict__ rs) {
    const int wid = threadIdx.x >> 6, lane = threadIdx.x & 63;
    const int r = blockIdx.x * 4 + wid;            // 0..2047
    const bool isA = (r < 1024);
    const int row = isA ? r : (r - 1024);
    const float* src = (isA ? x1 : x2) + (size_t)row * 256;

    float4 g = *(const float4*)(src + 4 * lane);
    const float k = 255.0f;
    unsigned q0 = (unsigned)(k / (1.0f + __expf(-g.x)) + 0.5f);
    unsigned q1 = (unsigned)(k / (1.0f + __expf(-g.y)) + 0.5f);
    unsigned q2 = (unsigned)(k / (1.0f + __expf(-g.z)) + 0.5f);
    unsigned q3 = (unsigned)(k / (1.0f + __expf(-g.w)) + 0.5f);

    (isA ? Aq : Bq)[(size_t)row * 64 + lane] = q0 | (q1 << 8) | (q2 << 16) | (q3 << 24);

    int sum = (int)(q0 + q1 + q2 + q3);
    #pragma unroll
    for (int s = 32; s >= 1; s >>= 1)
        sum += __shfl_xor(sum, s, 64);
    if (lane == 0) rs[r] = (float)sum;             // <= 65280: f32-exact
}

// ---- main: B in LDS, A from L1-resident global, quad-DPP reduce, 1 barrier ----
__global__ __launch_bounds__(256, 4)
void jaccard_main(const uint4* __restrict__ AqU4, const uint4* __restrict__ BqU4,
                  const float* __restrict__ rs, float* __restrict__ out) {
    __shared__ char BTile[TILEB];

    const int bi = blockIdx.x, bj = blockIdx.y;    // 32 x 32 tiles
    const int tid = threadIdx.x;

    // ---- stage B tile only: 2 coalesced uint4 loads + 2 b128 LDS writes ----
    #pragma unroll
    for (int k = 0; k < 2; ++k) {
        const int flat = tid + 256 * k;            // 0..511
        const int row = flat >> 4, c16 = flat & 15;
        uint4 vb = BqU4[(size_t)(bj * 32 + row) * 16 + c16];
        *(uint4*)(BTile + row * RSTR + c16 * 16) = vb;
    }
    __syncthreads();

    // lane roles: ql = D-quarter (chunks [4ql,4ql+4)); spatial (ty,tx) microtile 4x4
    const int lane = tid & 63;
    const int w    = tid >> 6;                 // 0..3
    const int ql   = lane & 3;
    const int sp   = (w << 4) | (lane >> 2);   // spatial 0..63
    const int tx   = sp & 7;                   // cols {tx + 8n}
    const int ty   = sp >> 3;                  // rows {ty + 8m}

    const char* bb = BTile + tx * RSTR + ql * 64;
    const int arow0 = bi * 32 + ty;            // + 8m

    unsigned acc[4][4] = {};
    #pragma unroll
    for (int cc = 0; cc < 4; ++cc) {
        const int c = ql * 4 + cc;             // A chunk index within row
        uint4 av[4], bv[4];
        #pragma unroll
        for (int m = 0; m < 4; ++m)
            av[m] = AqU4[(size_t)(arow0 + 8 * m) * 16 + c];           // L1-hit gather
        #pragma unroll
        for (int n = 0; n < 4; ++n)
            bv[n] = *(const uint4*)(bb + n * (8 * RSTR) + cc * 16);   // LDS
        #pragma unroll
        for (int m = 0; m < 4; ++m)
            #pragma unroll
            for (int n = 0; n < 4; ++n) {
                unsigned a = acc[m][n];
                a = sad8(av[m].x, bv[n].x, a);
                a = sad8(av[m].y, bv[n].y, a);
                a = sad8(av[m].z, bv[n].z, a);
                a = sad8(av[m].w, bv[n].w, a);
                acc[m][n] = a;
            }
    }

    // ---- cross-quarter reduce (DPP); lane ql keeps row m = ql ----
    unsigned sd[4];
    #pragma unroll
    for (int n = 0; n < 4; ++n) {
        unsigned r0 = quad_reduce_add(acc[0][n]);
        unsigned r1 = quad_reduce_add(acc[1][n]);
        unsigned r2 = quad_reduce_add(acc[2][n]);
        unsigned r3 = quad_reduce_add(acc[3][n]);
        sd[n] = ql < 2 ? (ql == 0 ? r0 : r1) : (ql == 2 ? r2 : r3);  // static + cndmask
    }

    // ---- epilogue: this lane owns row i = arow0 + 8*ql, cols {bj*32 + tx + 8n} ----
    const int i  = arow0 + 8 * ql;
    const int j0 = bj * 32 + tx;
    const float sa = rs[i];
    float* outT = out + (size_t)1024 * 1024;

    #pragma unroll
    for (int n = 0; n < 4; ++n) {
        const int j = j0 + 8 * n;
        const float sb = rs[1024 + j];
        const float t  = sa + sb;
        const float in = 0.5f * (t - (float)sd[n]);
        const float v  = in / (t - in);
        out [(size_t)i * 1024 + j] = v;
        outT[(size_t)j * 1024 + i] = v;
    }
}

extern "C" void kernel_launch(void* const* d_in, const int* in_sizes, int n_in,
                              void* d_out, int out_size, void* d_ws, size_t ws_size,
                              hipStream_t stream) {
    const float* x1 = (const float*)d_in[0];
    const float* x2 = (const float*)d_in[1];
    float* out = (float*)d_out;

    unsigned* Aq = (unsigned*)d_ws;                 // 256 KB row-major u8 A
    unsigned* Bq = Aq + (size_t)1024 * 64;          // 256 KB row-major u8 B
    float*    rs = (float*)(Bq + (size_t)1024 * 64);// 8 KB row sums

    prepass<<<512, 256, 0, stream>>>(x1, x2, Aq, Bq, rs);
    jaccard_main<<<dim3(32, 32), 256, 0, stream>>>((const uint4*)Aq, (const uint4*)Bq,
                                                   rs, out);
}

// Round 19
// 17.098 us; speedup vs baseline: 1.5025x; 1.1020x over previous
//
#include <hip/hip_runtime.h>
#include <math.h>

#define RSTR  272                  // u8 tile row stride: 17 x 16B groups -> even bank spread
#define TILEB (32 * RSTR)          // 8704 B per tile; total LDS = 17408 B -> 8 blocks/CU

// v_sad_u8: d = c + sum_k |a.byte[k] - b.byte[k]|
__device__ __forceinline__ unsigned sad8(unsigned a, unsigned b, unsigned c) {
    unsigned d;
    asm("v_sad_u8 %0, %1, %2, %3" : "=v"(d) : "v"(a), "v"(b), "v"(c));
    return d;
}

// quad-perm DPP butterfly add over lane quads (pure VALU, verified R14)
__device__ __forceinline__ unsigned quad_reduce_add(unsigned v) {
    unsigned t = (unsigned)__builtin_amdgcn_mov_dpp((int)v, 0xB1, 0xF, 0xF, false); // [1,0,3,2]
    v += t;
    t = (unsigned)__builtin_amdgcn_mov_dpp((int)v, 0x4E, 0xF, 0xF, false);          // [2,3,0,1]
    return v + t;
}

// ---- prepass: sigmoid -> u8 (x255, round) + integer row sums (f32-exact) ----
__global__ __launch_bounds__(256)
void prepass(const float* __restrict__ x1, const float* __restrict__ x2,
             unsigned* __restrict__ Aq, unsigned* __restrict__ Bq,
             float* __restrict__ rs) {
    const int wid = threadIdx.x >> 6, lane = threadIdx.x & 63;
    const int r = blockIdx.x * 4 + wid;            // 0..2047
    const bool isA = (r < 1024);
    const int row = isA ? r : (r - 1024);
    const float* src = (isA ? x1 : x2) + (size_t)row * 256;

    float4 g = *(const float4*)(src + 4 * lane);
    const float k = 255.0f;
    unsigned q0 = (unsigned)(k / (1.0f + __expf(-g.x)) + 0.5f);
    unsigned q1 = (unsigned)(k / (1.0f + __expf(-g.y)) + 0.5f);
    unsigned q2 = (unsigned)(k / (1.0f + __expf(-g.z)) + 0.5f);
    unsigned q3 = (unsigned)(k / (1.0f + __expf(-g.w)) + 0.5f);

    (isA ? Aq : Bq)[(size_t)row * 64 + lane] = q0 | (q1 << 8) | (q2 << 16) | (q3 << 24);

    int sum = (int)(q0 + q1 + q2 + q3);
    #pragma unroll
    for (int s = 32; s >= 1; s >>= 1)
        sum += __shfl_xor(sum, s, 64);
    if (lane == 0) rs[r] = (float)sum;             // <= 65280: f32-exact
}

// ---- main: A+B in LDS, quarter-in-quad + DPP reduce, 1 barrier, 8 blocks/CU ----
__global__ __launch_bounds__(256, 8)
void jaccard_main(const uint4* __restrict__ AqU4, const uint4* __restrict__ BqU4,
                  const float* __restrict__ rs, float* __restrict__ out) {
    __shared__ char ATile[TILEB];
    __shared__ char BTile[TILEB];

    const int bi = blockIdx.x, bj = blockIdx.y;    // 32 x 32 tiles
    const int tid = threadIdx.x;

    // ---- staging: 2 coalesced uint4 loads + 2 b128 LDS writes per thread ----
    #pragma unroll
    for (int k = 0; k < 2; ++k) {
        const int flat = tid + 256 * k;            // 0..511
        const int row = flat >> 4, c16 = flat & 15;
        uint4 va = AqU4[(size_t)(bi * 32 + row) * 16 + c16];
        *(uint4*)(ATile + row * RSTR + c16 * 16) = va;
        uint4 vb = BqU4[(size_t)(bj * 32 + row) * 16 + c16];
        *(uint4*)(BTile + row * RSTR + c16 * 16) = vb;
    }
    __syncthreads();

    // lane roles: quad = 4 quarters of one spatial position
    const int lane = tid & 63;
    const int w    = tid >> 6;                 // 0..3
    const int ql   = lane & 3;                 // D-quarter: bytes [64ql, 64ql+64)
    const int sp   = (w << 4) | (lane >> 2);   // spatial 0..63
    const int tx   = sp & 7;                   // cols {tx + 8n}
    const int ty   = sp >> 3;                  // rows {ty + 8m}

    const char* abase = ATile + ty * RSTR + ql * 64;
    const char* bbase = BTile + tx * RSTR + ql * 64;

    unsigned acc[4][4] = {};
    #pragma unroll
    for (int cc = 0; cc < 4; ++cc) {               // 4 x 16B chunks per quarter
        uint4 bv[4];
        #pragma unroll
        for (int n = 0; n < 4; ++n)
            bv[n] = *(const uint4*)(bbase + n * (8 * RSTR) + cc * 16);
        #pragma unroll
        for (int m = 0; m < 4; ++m) {
            uint4 av = *(const uint4*)(abase + m * (8 * RSTR) + cc * 16);
            #pragma unroll
            for (int n = 0; n < 4; ++n) {
                unsigned a = acc[m][n];
                a = sad8(av.x, bv[n].x, a);
                a = sad8(av.y, bv[n].y, a);
                a = sad8(av.z, bv[n].z, a);
                a = sad8(av.w, bv[n].w, a);
                acc[m][n] = a;
            }
        }
    }

    // ---- cross-quarter reduce (DPP over lane quads); lane ql keeps row m = ql ----
    unsigned sd[4];
    #pragma unroll
    for (int n = 0; n < 4; ++n) {
        unsigned r0 = quad_reduce_add(acc[0][n]);
        unsigned r1 = quad_reduce_add(acc[1][n]);
        unsigned r2 = quad_reduce_add(acc[2][n]);
        unsigned r3 = quad_reduce_add(acc[3][n]);
        sd[n] = ql < 2 ? (ql == 0 ? r0 : r1) : (ql == 2 ? r2 : r3);  // static + cndmask
    }

    // ---- epilogue: this lane owns row i = bi*32 + ty + 8*ql, cols {bj*32+tx+8n} ----
    const int i  = bi * 32 + ty + 8 * ql;
    const int j0 = bj * 32 + tx;
    const float sa = rs[i];
    float* outT = out + (size_t)1024 * 1024;

    #pragma unroll
    for (int n = 0; n < 4; ++n) {
        const int j = j0 + 8 * n;
        const float sb = rs[1024 + j];
        const float t  = sa + sb;
        const float in = 0.5f * (t - (float)sd[n]);
        const float v  = in / (t - in);
        out [(size_t)i * 1024 + j] = v;
        outT[(size_t)j * 1024 + i] = v;
    }
}

extern "C" void kernel_launch(void* const* d_in, const int* in_sizes, int n_in,
                              void* d_out, int out_size, void* d_ws, size_t ws_size,
                              hipStream_t stream) {
    const float* x1 = (const float*)d_in[0];
    const float* x2 = (const float*)d_in[1];
    float* out = (float*)d_out;

    unsigned* Aq = (unsigned*)d_ws;                 // 256 KB row-major u8 A
    unsigned* Bq = Aq + (size_t)1024 * 64;          // 256 KB row-major u8 B
    float*    rs = (float*)(Bq + (size_t)1024 * 64);// 8 KB row sums

    prepass<<<512, 256, 0, stream>>>(x1, x2, Aq, Bq, rs);
    jaccard_main<<<dim3(32, 32), 256, 0, stream>>>((const uint4*)Aq, (const uint4*)Bq,
                                                   rs, out);
}

// Round 21
// 15.772 us; speedup vs baseline: 1.6289x; 1.0841x over previous
//
#include <hip/hip_runtime.h>
#include <math.h>

#define RSTR  272                  // u8 tile row stride: 17 x 16B groups
#define TILEB (32 * RSTR)          // 8704 B per tile (32 rows)
#define PSTR  136                  // partial stride per spatial lane: 4q*32B + 8 pad

// v_sad_u8: d = c + sum_k |a.byte[k] - b.byte[k]|
__device__ __forceinline__ unsigned sad8(unsigned a, unsigned b, unsigned c) {
    unsigned d;
    asm("v_sad_u8 %0, %1, %2, %3" : "=v"(d) : "v"(a), "v"(b), "v"(c));
    return d;
}

// ---- prepass: sigmoid -> u8 (x255, round) + integer row sums (f32-exact) ----
__global__ __launch_bounds__(256)
void prepass(const float* __restrict__ x1, const float* __restrict__ x2,
             unsigned* __restrict__ Aq, unsigned* __restrict__ Bq,
             float* __restrict__ rs) {
    const int wid = threadIdx.x >> 6, lane = threadIdx.x & 63;
    const int r = blockIdx.x * 4 + wid;            // 0..2047
    const bool isA = (r < 1024);
    const int row = isA ? r : (r - 1024);
    const float* src = (isA ? x1 : x2) + (size_t)row * 256;

    float4 g = *(const float4*)(src + 4 * lane);
    const float k = 255.0f;
    unsigned q0 = (unsigned)(k / (1.0f + __expf(-g.x)) + 0.5f);
    unsigned q1 = (unsigned)(k / (1.0f + __expf(-g.y)) + 0.5f);
    unsigned q2 = (unsigned)(k / (1.0f + __expf(-g.z)) + 0.5f);
    unsigned q3 = (unsigned)(k / (1.0f + __expf(-g.w)) + 0.5f);

    (isA ? Aq : Bq)[(size_t)row * 64 + lane] = q0 | (q1 << 8) | (q2 << 16) | (q3 << 24);

    int sum = (int)(q0 + q1 + q2 + q3);
    #pragma unroll
    for (int s = 32; s >= 1; s >>= 1)
        sum += __shfl_xor(sum, s, 64);
    if (lane == 0) rs[r] = (float)sum;             // <= 65280: f32-exact
}

// ---- main: 32x32 tiles, 256-thread blocks, 4 blocks/CU for phase overlap ----
__global__ __launch_bounds__(256, 4)
void jaccard_main(const uint4* __restrict__ Aq, const uint4* __restrict__ Bq,
                  const float* __restrict__ rs, float* __restrict__ out) {
    __shared__ char ATile[TILEB];
    __shared__ char BTile[TILEB];
    __shared__ char Part[64 * PSTR];   // [s 64][q 4][m 4] uint2

    const int bi = blockIdx.x, bj = blockIdx.y;    // 32 x 32 tiles
    const int tid = threadIdx.x;

    // ---- staging: 2 uint4 loads + 2 b128 LDS writes per thread per tile ----
    #pragma unroll
    for (int k = 0; k < 2; ++k) {
        const int flat = tid + 256 * k;            // 0..511
        const int row = flat >> 4, c16 = flat & 15;
        uint4 va = Aq[(size_t)(bi * 32 + row) * 16 + c16];
        *(uint4*)(ATile + row * RSTR + c16 * 16) = va;
        uint4 vb = Bq[(size_t)(bj * 32 + row) * 16 + c16];
        *(uint4*)(BTile + row * RSTR + c16 * 16) = vb;
    }
    __syncthreads();

    // wave = one D-quarter q (bytes [64q,64q+64)); spatial 8x8, microtile 4x4
    const int s  = tid & 63;
    const int q  = tid >> 6;        // 0..3, wave-uniform
    const int tx = s & 7;           // cols {tx + 8n}
    const int ty = s >> 3;          // rows {ty + 8m}

    const char* ab = ATile + ty * RSTR + q * 64;
    const char* bb = BTile + tx * RSTR + q * 64;

    unsigned acc[4][4] = {};
    #pragma unroll
    for (int cc = 0; cc < 4; ++cc) {               // 4 x 16B chunks per quarter
        uint4 av[4], bv[4];
        #pragma unroll
        for (int m = 0; m < 4; ++m)
            av[m] = *(const uint4*)(ab + m * (8 * RSTR) + cc * 16);   // 8-addr broadcast
        #pragma unroll
        for (int n = 0; n < 4; ++n)
            bv[n] = *(const uint4*)(bb + n * (8 * RSTR) + cc * 16);   // 8-addr broadcast
        #pragma unroll
        for (int m = 0; m < 4; ++m)
            #pragma unroll
            for (int n = 0; n < 4; ++n) {
                unsigned a = acc[m][n];
                a = sad8(av[m].x, bv[n].x, a);
                a = sad8(av[m].y, bv[n].y, a);
                a = sad8(av[m].z, bv[n].z, a);
                a = sad8(av[m].w, bv[n].w, a);
                acc[m][n] = a;
            }
    }

    // ---- partials: u16-packed [s][q][m], b64 each; 136B stride -> 2-way banks ----
    {
        char* pw = Part + s * PSTR + q * 32;
        #pragma unroll
        for (int m = 0; m < 4; ++m) {
            unsigned p0 = acc[m][0] | (acc[m][1] << 16);   // each <= 16320
            unsigned p1 = acc[m][2] | (acc[m][3] << 16);
            *(uint2*)(pw + m * 8) = make_uint2(p0, p1);
        }
    }
    __syncthreads();

    // ---- reduce + epilogue: thread (s2, m2) owns row ty2+8*m2, cols {tx2+8n} ----
    const int s2 = tid & 63;
    const int m2 = tid >> 6;
    const int tx2 = s2 & 7;
    const int ty2 = s2 >> 3;

    unsigned sd0 = 0, sd1 = 0, sd2 = 0, sd3 = 0;
    const char* pr = Part + s2 * PSTR + m2 * 8;
    #pragma unroll
    for (int qq = 0; qq < 4; ++qq) {
        uint2 p = *(const uint2*)(pr + qq * 32);
        sd0 += p.x & 0xffff; sd1 += p.x >> 16;
        sd2 += p.y & 0xffff; sd3 += p.y >> 16;
    }

    const int i  = bi * 32 + ty2 + 8 * m2;
    const int j0 = bj * 32 + tx2;

    const float sa  = rs[i];
    const float sb0 = rs[1024 + j0];
    const float sb1 = rs[1024 + j0 + 8];
    const float sb2 = rs[1024 + j0 + 16];
    const float sb3 = rs[1024 + j0 + 24];

    const float t0 = sa + sb0, t1 = sa + sb1, t2 = sa + sb2, t3 = sa + sb3;
    const float i0 = 0.5f * (t0 - (float)sd0);
    const float i1 = 0.5f * (t1 - (float)sd1);
    const float i2 = 0.5f * (t2 - (float)sd2);
    const float i3 = 0.5f * (t3 - (float)sd3);
    const float v0 = i0 / (t0 - i0);
    const float v1 = i1 / (t1 - i1);
    const float v2 = i2 / (t2 - i2);
    const float v3 = i3 / (t3 - i3);

    float* outT = out + (size_t)1024 * 1024;
    out[(size_t)i * 1024 + j0]      = v0;
    out[(size_t)i * 1024 + j0 + 8]  = v1;
    out[(size_t)i * 1024 + j0 + 16] = v2;
    out[(size_t)i * 1024 + j0 + 24] = v3;
    outT[(size_t)j0        * 1024 + i] = v0;
    outT[(size_t)(j0 + 8)  * 1024 + i] = v1;
    outT[(size_t)(j0 + 16) * 1024 + i] = v2;
    outT[(size_t)(j0 + 24) * 1024 + i] = v3;
}

extern "C" void kernel_launch(void* const* d_in, const int* in_sizes, int n_in,
                              void* d_out, int out_size, void* d_ws, size_t ws_size,
                              hipStream_t stream) {
    const float* x1 = (const float*)d_in[0];
    const float* x2 = (const float*)d_in[1];
    float* out = (float*)d_out;

    unsigned* Aq = (unsigned*)d_ws;                 // 256 KB
    unsigned* Bq = Aq + (size_t)1024 * 64;          // 256 KB
    float*    rs = (float*)(Bq + (size_t)1024 * 64);// 8 KB

    prepass<<<512, 256, 0, stream>>>(x1, x2, Aq, Bq, rs);
    jaccard_main<<<dim3(32, 32), 256, 0, stream>>>((const uint4*)Aq, (const uint4*)Bq,
                                                   rs, out);
}